// Round 1
// 1230.228 us; speedup vs baseline: 1.9433x; 1.9433x over previous
//
#include <hip/hip_runtime.h>
#include <hip/hip_bf16.h>

// Problem constants (fp32 I/O; bf16 internally for MFMA)
#define LAT    256
#define HID    1024
#define TSTEPS 10
#define MTOT   16384            // 32*512 trajectory rows (corrcoef rows sliced away)
#define RPB    64               // rows per block
#define NBLK   (MTOT/RPB)       // 256 blocks = 1 per CU (96 KB LDS forces 1/CU anyway)
#define CHUNK  256              // HIDDEN chunk held in LDS
#define NCHUNK (HID/CHUNK)      // 4

typedef short bf16x8 __attribute__((ext_vector_type(8)));
typedef float f32x4  __attribute__((ext_vector_type(4)));

__device__ __forceinline__ unsigned short f2bfu(float f) {
    __hip_bfloat16 h = __float2bfloat16(f);
    unsigned short u; __builtin_memcpy(&u, &h, 2); return u;
}

// XOR-swizzled byte offset into a [64][256] bf16 LDS tile (row stride 512 B).
// Unswizzled, the 16-row x 16B A-fragment ds_read_b128 lands on 16 of 128 B
// of bank space (2x serialization); XOR of bits 4..6 with row%8 restores the
// optimal 8-words/bank pattern (G4/T2). Bijective per row; preserves 16B
// alignment for reads and low 4 bits for b16 writes.
__device__ __forceinline__ int swz(int row, int kb) {
    return row * 512 + (kb ^ ((row & 7) << 4));
}

// ---- weight repack: src [K][N] f32  ->  dst fragment-linear bf16 tiles ----
// Tile (tn, tk) = 16 n-rows x 32 k-cols, stored lane-ordered so a wave's
// B-fragment load is one fully-coalesced 1 KB global_load_dwordx4 burst:
// dst[(tn*(K/32)+tk)*512 + (q*16+l16)*8 + j] = bf16(src[(tk*32+q*8+j)*N + tn*16+l16])
__global__ void pack_kernel(const float* __restrict__ src,
                            __hip_bfloat16* __restrict__ dst,
                            int N, int K) {
    int i = blockIdx.x * blockDim.x + threadIdx.x;
    if (i >= N * K) return;
    int KT   = K >> 5;
    int tile = i >> 9, wi = i & 511;
    int lane8 = wi >> 3, j = wi & 7;
    int q = lane8 >> 4, l16 = lane8 & 15;
    int tn = tile / KT, tk = tile - tn * KT;
    int n = tn * 16 + l16;
    int k = tk * 32 + q * 8 + j;
    dst[i] = __float2bfloat16(src[(size_t)k * N + n]);
}

// ---- persistent fused RK4 integrator -------------------------------------
// Grid 256 x 512 threads (8 waves, 2/SIMD). Block owns 64 rows; each row
// evolves independently (f is row-wise), so no inter-block communication.
// Per eval: for each 256-col HIDDEN chunk:
//   phase A: Hc = tanh(Xs @ W1[:,chunk] + b1)   (Xs in LDS, W1 from L2)
//   barrier
//   phase B: k += Hc @ W2[chunk,:]              (Hc in LDS, W2 preloaded)
// Hc double-buffered -> one barrier per chunk. x/ksum/k stay in registers.
__global__ __launch_bounds__(512)
void ode_kernel(const float* __restrict__ fp,
                const float* __restrict__ ts,
                const __hip_bfloat16* __restrict__ W1p,   // packed, [HID/16][LAT/32] tiles
                const float* __restrict__ bias1,
                const __hip_bfloat16* __restrict__ W2p,   // packed, [LAT/16][HID/32] tiles
                float* __restrict__ out) {
    __shared__ __align__(16) unsigned short Xs_s[64 * 256];      // 32 KB
    __shared__ __align__(16) unsigned short Hc_s[2][64 * 256];   // 64 KB
    char* XsB  = (char*)Xs_s;
    char* Hc0B = (char*)Hc_s[0];
    char* Hc1B = (char*)Hc_s[1];

    const int tid  = threadIdx.x;
    const int lane = tid & 63;
    const int wave = tid >> 6;            // 0..7, owns state cols [wave*32, +32)
    const int q = lane >> 4, l16 = lane & 15;
    const int grow0 = blockIdx.x * RPB;

    // Per-thread state element ownership (MFMA C/D layout):
    //   row = mt*16 + q*4 + r,  col = wave*32 + nt*16 + l16
    f32x4 x_[4][2], ksum[4][2], kacc[4][2];

    // load x from first_point, emit t=0 output slice, build Xs0 = bf16(x)
    #pragma unroll
    for (int mt = 0; mt < 4; ++mt) {
        #pragma unroll
        for (int nt = 0; nt < 2; ++nt) {
            const int col = wave * 32 + nt * 16 + l16;
            #pragma unroll
            for (int r = 0; r < 4; ++r) {
                const int row = mt * 16 + q * 4 + r;
                float v = fp[(size_t)(grow0 + row) * LAT + col];
                x_[mt][nt][r] = v;
                out[((size_t)(grow0 + row) * TSTEPS) * LAT + col] = v;
                *(unsigned short*)(XsB + swz(row, col * 2)) = f2bfu(v);
            }
        }
    }
    __syncthreads();

    // packed-weight per-lane base pointers (advance by tile = 512 elems)
    // W1p tile (tn = kc*16 + wave*2 + nt, tk = kk), KT=8
    const __hip_bfloat16* w1b0 = W1p + (size_t)(wave * 2 + 0) * 8 * 512 + lane * 8;
    const __hip_bfloat16* w1b1 = W1p + (size_t)(wave * 2 + 1) * 8 * 512 + lane * 8;
    // W2p tile (tn = wave*2 + nt, tk = kc*8 + kk), KT=32
    const __hip_bfloat16* w2b0 = W2p + (size_t)(wave * 2 + 0) * 32 * 512 + lane * 8;
    const __hip_bfloat16* w2b1 = W2p + (size_t)(wave * 2 + 1) * 32 * 512 + lane * 8;

    #pragma unroll 1
    for (int step = 0; step < TSTEPS - 1; ++step) {
        const float dt = ts[step + 1] - ts[step];

        #pragma unroll 1
        for (int s = 0; s < 4; ++s) {
            // ---------------- eval: kacc = f(Xs) ----------------
            #pragma unroll
            for (int mt = 0; mt < 4; ++mt) {
                kacc[mt][0] = (f32x4){0.f, 0.f, 0.f, 0.f};
                kacc[mt][1] = (f32x4){0.f, 0.f, 0.f, 0.f};
            }

            #pragma unroll 1
            for (int kc = 0; kc < NCHUNK; ++kc) {
                char* HcB = (kc & 1) ? Hc1B : Hc0B;

                // ---- phase A: a1 = Xs @ W1 chunk (wave's 32-col n-slice) ----
                const __hip_bfloat16* w1c0 = w1b0 + (size_t)kc * 16 * 8 * 512;
                const __hip_bfloat16* w1c1 = w1b1 + (size_t)kc * 16 * 8 * 512;
                f32x4 a1[4][2];
                #pragma unroll
                for (int mt = 0; mt < 4; ++mt) {
                    a1[mt][0] = (f32x4){0.f, 0.f, 0.f, 0.f};
                    a1[mt][1] = (f32x4){0.f, 0.f, 0.f, 0.f};
                }
                #pragma unroll
                for (int kk = 0; kk < 8; ++kk) {
                    bf16x8 b0 = *(const bf16x8*)(w1c0 + kk * 512);
                    bf16x8 b1 = *(const bf16x8*)(w1c1 + kk * 512);
                    #pragma unroll
                    for (int mt = 0; mt < 4; ++mt) {
                        bf16x8 av = *(const bf16x8*)(XsB + swz(mt * 16 + l16, kk * 64 + q * 16));
                        a1[mt][0] = __builtin_amdgcn_mfma_f32_16x16x32_bf16(av, b0, a1[mt][0], 0, 0, 0);
                        a1[mt][1] = __builtin_amdgcn_mfma_f32_16x16x32_bf16(av, b1, a1[mt][1], 0, 0, 0);
                    }
                }

                // bias + tanh -> Hc (bf16, swizzled)
                const float bv0 = bias1[kc * CHUNK + wave * 32 + l16];
                const float bv1 = bias1[kc * CHUNK + wave * 32 + 16 + l16];
                #pragma unroll
                for (int mt = 0; mt < 4; ++mt) {
                    #pragma unroll
                    for (int nt = 0; nt < 2; ++nt) {
                        const float bv = nt ? bv1 : bv0;
                        const int col = wave * 32 + nt * 16 + l16;
                        #pragma unroll
                        for (int r = 0; r < 4; ++r) {
                            const int row = mt * 16 + q * 4 + r;
                            float v = a1[mt][nt][r] + bv;
                            float e = __expf(2.f * v);
                            float th = 1.f - 2.f / (e + 1.f);       // tanh(v)
                            *(unsigned short*)(HcB + swz(row, col * 2)) = f2bfu(th);
                        }
                    }
                }

                // preload W2 fragments for this chunk BEFORE the barrier so the
                // L2 latency hides under the barrier + phase-B LDS reads
                bf16x8 w2f0[8], w2f1[8];
                #pragma unroll
                for (int kk = 0; kk < 8; ++kk) {
                    w2f0[kk] = *(const bf16x8*)(w2b0 + (size_t)(kc * 8 + kk) * 512);
                    w2f1[kk] = *(const bf16x8*)(w2b1 + (size_t)(kc * 8 + kk) * 512);
                }

                __syncthreads();

                // ---- phase B: kacc += Hc @ W2 chunk ----
                #pragma unroll
                for (int kk = 0; kk < 8; ++kk) {
                    #pragma unroll
                    for (int mt = 0; mt < 4; ++mt) {
                        bf16x8 av = *(const bf16x8*)(HcB + swz(mt * 16 + l16, kk * 64 + q * 16));
                        kacc[mt][0] = __builtin_amdgcn_mfma_f32_16x16x32_bf16(av, w2f0[kk], kacc[mt][0], 0, 0, 0);
                        kacc[mt][1] = __builtin_amdgcn_mfma_f32_16x16x32_bf16(av, w2f1[kk], kacc[mt][1], 0, 0, 0);
                    }
                }
                // no barrier here: next chunk writes the other Hc buffer, and the
                // per-chunk A->B barrier transitively protects buffer reuse.
            }

            // ---------------- RK4 combine + next stage input ----------------
            if (s < 3) {
                const float cw = (s == 2) ? dt : 0.5f * dt;
                #pragma unroll
                for (int mt = 0; mt < 4; ++mt) {
                    #pragma unroll
                    for (int nt = 0; nt < 2; ++nt) {
                        if (s == 0) ksum[mt][nt] = kacc[mt][nt];
                        else        ksum[mt][nt] += 2.f * kacc[mt][nt];
                        const int col = wave * 32 + nt * 16 + l16;
                        #pragma unroll
                        for (int r = 0; r < 4; ++r) {
                            const int row = mt * 16 + q * 4 + r;
                            float xv = x_[mt][nt][r] + cw * kacc[mt][nt][r];
                            *(unsigned short*)(XsB + swz(row, col * 2)) = f2bfu(xv);
                        }
                    }
                }
            } else {
                const float d6 = dt * (1.f / 6.f);
                #pragma unroll
                for (int mt = 0; mt < 4; ++mt) {
                    #pragma unroll
                    for (int nt = 0; nt < 2; ++nt) {
                        const int col = wave * 32 + nt * 16 + l16;
                        #pragma unroll
                        for (int r = 0; r < 4; ++r) {
                            const int row = mt * 16 + q * 4 + r;
                            float xv = x_[mt][nt][r] + d6 * (ksum[mt][nt][r] + kacc[mt][nt][r]);
                            x_[mt][nt][r] = xv;
                            out[((size_t)(grow0 + row) * TSTEPS + (step + 1)) * LAT + col] = xv;
                            *(unsigned short*)(XsB + swz(row, col * 2)) = f2bfu(xv);
                        }
                    }
                }
            }
            __syncthreads();   // Xs fully written before next eval reads it
        }
    }
}

extern "C" void kernel_launch(void* const* d_in, const int* in_sizes, int n_in,
                              void* d_out, int out_size, void* d_ws, size_t ws_size,
                              hipStream_t stream) {
    (void)in_sizes; (void)n_in; (void)out_size; (void)ws_size;
    const float* fp = (const float*)d_in[0];
    const float* ts = (const float*)d_in[1];
    const float* W1 = (const float*)d_in[2];
    const float* b1 = (const float*)d_in[3];
    const float* W2 = (const float*)d_in[4];
    float* out = (float*)d_out;

    __hip_bfloat16* W1p = (__hip_bfloat16*)d_ws;                 // 512 KB
    __hip_bfloat16* W2p = W1p + (size_t)HID * LAT;               // 512 KB

    // W1: B-operand n-dim = HID, k-dim = LAT; src W1 is [LAT][HID] = [K][N]
    pack_kernel<<<(HID * LAT) / 256, 256, 0, stream>>>(W1, W1p, HID, LAT);
    // W2: B-operand n-dim = LAT, k-dim = HID; src W2 is [HID][LAT] = [K][N]
    pack_kernel<<<(HID * LAT) / 256, 256, 0, stream>>>(W2, W2p, LAT, HID);

    ode_kernel<<<NBLK, 512, 0, stream>>>(fp, ts, W1p, b1, W2p, out);
}

// Round 2
// 1208.811 us; speedup vs baseline: 1.9777x; 1.0177x over previous
//
#include <hip/hip_runtime.h>
#include <hip/hip_bf16.h>

// Problem constants (fp32 I/O; bf16 internally for MFMA)
#define LAT    256
#define HID    1024
#define TSTEPS 10
#define MTOT   16384            // 32*512 trajectory rows (corrcoef rows sliced away)
#define RPB    64               // rows per block
#define NBLK   (MTOT/RPB)       // 256 blocks = 1 per CU (96 KB LDS forces 1/CU)
#define CHUNK  256              // HIDDEN chunk held in LDS
#define NCHUNK (HID/CHUNK)      // 4

typedef short bf16x8 __attribute__((ext_vector_type(8)));
typedef float f32x4  __attribute__((ext_vector_type(4)));

__device__ __forceinline__ unsigned short f2bfu(float f) {
    __hip_bfloat16 h = __float2bfloat16(f);
    unsigned short u; __builtin_memcpy(&u, &h, 2); return u;
}

// pack 4 f32 -> 4 bf16 -> one 8-byte LDS store (ds_write_b64)
__device__ __forceinline__ void st4bf(char* p, float a, float b, float c, float d) {
    union { unsigned int u[2]; unsigned long long ull; } pk;
    pk.u[0] = (unsigned)f2bfu(a) | ((unsigned)f2bfu(b) << 16);
    pk.u[1] = (unsigned)f2bfu(c) | ((unsigned)f2bfu(d) << 16);
    *(unsigned long long*)p = pk.ull;
}

// XOR-swizzled byte offset into a [64][256] bf16 LDS tile (row stride 512 B).
// XOR of byte bits 4..6 with row%8 spreads the 512B-strided rows across the
// 128B bank window; verified balanced for b128 row-reads, b64 packed writes.
__device__ __forceinline__ int swz(int row, int kb) {
    return row * 512 + (kb ^ ((row & 7) << 4));
}

// ---- weight repack: src [K][N] f32  ->  dst fragment-linear bf16 tiles ----
// Tile (tn, tk) = 16 n-rows x 32 k-cols, lane-ordered: one wave fragment =
// one coalesced 1 KB burst. The same tile serves as A-operand (row=n, k
// contiguous) for the swapped-operand MFMA.
// dst[(tn*(K/32)+tk)*512 + (q*16+l16)*8 + j] = bf16(src[(tk*32+q*8+j)*N + tn*16+l16])
__global__ void pack_kernel(const float* __restrict__ src,
                            __hip_bfloat16* __restrict__ dst,
                            int N, int K) {
    int i = blockIdx.x * blockDim.x + threadIdx.x;
    if (i >= N * K) return;
    int KT   = K >> 5;
    int tile = i >> 9, wi = i & 511;
    int lane8 = wi >> 3, j = wi & 7;
    int q = lane8 >> 4, l16 = lane8 & 15;
    int tn = tile / KT, tk = tile - tn * KT;
    int n = tn * 16 + l16;
    int k = tk * 32 + q * 8 + j;
    dst[i] = __float2bfloat16(src[(size_t)k * N + n]);
}

// ---- persistent fused RK4 integrator, swapped-operand MFMA ---------------
// Grid 256 x 512 threads (8 waves, 2/SIMD; VGPR<=256 is free at this LDS).
// Wave split: wtraj = wave&1 owns traj 32-rows; wgrp = wave>>1 owns a 64-wide
// hid slice (phase A) / lat slice (phase B).
// Phase A: D'[hid][traj] = W1tile . Xs^T  (A = packed W1, B = Xs row-frags,
//          held in registers for the whole eval -> phase A has NO ds_reads).
// Phase B: D''[lat][traj] = W2tile . Hc^T (B-frags = Hc row-reads from LDS).
// Lane owns (traj = fixed, 4 consecutive hid/lat) -> all LDS writes are
// packed b64, state loads float4, out stores dwordx4.
__global__ __launch_bounds__(512, 2)
void ode_kernel(const float* __restrict__ fp,
                const float* __restrict__ ts,
                const __hip_bfloat16* __restrict__ W1p,   // [HID/16][LAT/32] tiles
                const float* __restrict__ bias1,
                const __hip_bfloat16* __restrict__ W2p,   // [LAT/16][HID/32] tiles
                float* __restrict__ out) {
    __shared__ __align__(16) unsigned short Xs_s[64 * 256];      // 32 KB
    __shared__ __align__(16) unsigned short Hc_s[2][64 * 256];   // 64 KB
    char* XsB  = (char*)Xs_s;
    char* Hc0B = (char*)Hc_s[0];
    char* Hc1B = (char*)Hc_s[1];

    const int tid   = threadIdx.x;
    const int lane  = tid & 63;
    const int wave  = tid >> 6;           // 0..7
    const int wtraj = wave & 1;           // traj group (32 rows)
    const int wgrp  = wave >> 1;          // 0..3: hid-64 (A) / lat-64 (B) group
    const int q = lane >> 4, l16 = lane & 15;
    const int grow0 = blockIdx.x * RPB;
    const int trow0 = wtraj * 32;

    // Per-thread state (element r): traj = trow0 + nt*16 + l16,
    //                               lat  = wgrp*64 + mt*16 + q*4 + r
    f32x4 x_[4][2], ksum[4][2], kacc[4][2];

    // init: float4 state load, t=0 output slice, packed b64 Xs build
    #pragma unroll
    for (int mt = 0; mt < 4; ++mt) {
        #pragma unroll
        for (int nt = 0; nt < 2; ++nt) {
            const int traj = trow0 + nt * 16 + l16;
            const int lat  = wgrp * 64 + mt * 16 + q * 4;
            float4 v = *(const float4*)(fp + (size_t)(grow0 + traj) * LAT + lat);
            x_[mt][nt] = (f32x4){v.x, v.y, v.z, v.w};
            *(float4*)(out + ((size_t)(grow0 + traj) * TSTEPS) * LAT + lat) = v;
            st4bf(XsB + swz(traj, lat * 2), v.x, v.y, v.z, v.w);
        }
    }
    __syncthreads();

    const __hip_bfloat16* w1l = W1p + lane * 8;   // + tile*512
    const __hip_bfloat16* w2l = W2p + lane * 8;

    #pragma unroll 1
    for (int step = 0; step < TSTEPS - 1; ++step) {
        const float dt = ts[step + 1] - ts[step];

        #pragma unroll 1
        for (int s = 0; s < 4; ++s) {
            // ---- load ALL Xs B-fragments for this eval into registers ----
            bf16x8 xf[2][8];
            #pragma unroll
            for (int nt = 0; nt < 2; ++nt)
                #pragma unroll
                for (int kk = 0; kk < 8; ++kk)
                    xf[nt][kk] = *(const bf16x8*)(XsB +
                        swz(trow0 + nt * 16 + l16, kk * 64 + q * 16));

            #pragma unroll
            for (int mt = 0; mt < 4; ++mt) {
                kacc[mt][0] = (f32x4){0.f, 0.f, 0.f, 0.f};
                kacc[mt][1] = (f32x4){0.f, 0.f, 0.f, 0.f};
            }

            #pragma unroll 1
            for (int kc = 0; kc < NCHUNK; ++kc) {
                char* HcB = (kc & 1) ? Hc1B : Hc0B;

                // ---- phase A: a1[hid-tile][traj-tile], no LDS reads ----
                f32x4 a1[4][2];
                #pragma unroll
                for (int mt = 0; mt < 4; ++mt) {
                    a1[mt][0] = (f32x4){0.f, 0.f, 0.f, 0.f};
                    a1[mt][1] = (f32x4){0.f, 0.f, 0.f, 0.f};
                }
                #pragma unroll
                for (int kk = 0; kk < 8; ++kk) {
                    bf16x8 w1f[4];
                    #pragma unroll
                    for (int mt = 0; mt < 4; ++mt)
                        w1f[mt] = *(const bf16x8*)(w1l +
                            (size_t)((kc * 16 + wgrp * 4 + mt) * 8 + kk) * 512);
                    #pragma unroll
                    for (int mt = 0; mt < 4; ++mt) {
                        a1[mt][0] = __builtin_amdgcn_mfma_f32_16x16x32_bf16(
                                        w1f[mt], xf[0][kk], a1[mt][0], 0, 0, 0);
                        a1[mt][1] = __builtin_amdgcn_mfma_f32_16x16x32_bf16(
                                        w1f[mt], xf[1][kk], a1[mt][1], 0, 0, 0);
                    }
                }

                // bias + tanh -> packed b64 Hc writes
                #pragma unroll
                for (int mt = 0; mt < 4; ++mt) {
                    float4 bb = *(const float4*)(bias1 +
                                    kc * CHUNK + wgrp * 64 + mt * 16 + q * 4);
                    const int kb = wgrp * 128 + mt * 32 + q * 8;
                    #pragma unroll
                    for (int nt = 0; nt < 2; ++nt) {
                        const int traj = trow0 + nt * 16 + l16;
                        float th[4];
                        #pragma unroll
                        for (int r = 0; r < 4; ++r) {
                            float bv = (r == 0) ? bb.x : (r == 1) ? bb.y
                                     : (r == 2) ? bb.z : bb.w;
                            float v = a1[mt][nt][r] + bv;
                            float e = __expf(2.f * v);
                            th[r] = 1.f - 2.f / (e + 1.f);   // tanh(v)
                        }
                        st4bf(HcB + swz(traj, kb), th[0], th[1], th[2], th[3]);
                    }
                }
                __syncthreads();   // Hc[kc] ready (also fences buf reuse)

                // ---- phase B: kacc[lat-tile][traj-tile] += W2 . Hc^T ----
                #pragma unroll
                for (int kk = 0; kk < 8; ++kk) {
                    bf16x8 w2f[4], hcf[2];
                    #pragma unroll
                    for (int mt = 0; mt < 4; ++mt)
                        w2f[mt] = *(const bf16x8*)(w2l +
                            (size_t)((wgrp * 4 + mt) * 32 + kc * 8 + kk) * 512);
                    #pragma unroll
                    for (int nt = 0; nt < 2; ++nt)
                        hcf[nt] = *(const bf16x8*)(HcB +
                            swz(trow0 + nt * 16 + l16, kk * 64 + q * 16));
                    #pragma unroll
                    for (int mt = 0; mt < 4; ++mt) {
                        kacc[mt][0] = __builtin_amdgcn_mfma_f32_16x16x32_bf16(
                                          w2f[mt], hcf[0], kacc[mt][0], 0, 0, 0);
                        kacc[mt][1] = __builtin_amdgcn_mfma_f32_16x16x32_bf16(
                                          w2f[mt], hcf[1], kacc[mt][1], 0, 0, 0);
                    }
                }
                // no trailing barrier: next chunk writes the other Hc buffer;
                // reuse at distance 2 is fenced by the intervening barrier.
            }

            // ---------------- RK4 combine + next stage input ----------------
            if (s < 3) {
                const float cw = (s == 2) ? dt : 0.5f * dt;
                #pragma unroll
                for (int mt = 0; mt < 4; ++mt) {
                    #pragma unroll
                    for (int nt = 0; nt < 2; ++nt) {
                        if (s == 0) ksum[mt][nt] = kacc[mt][nt];
                        else        ksum[mt][nt] += 2.f * kacc[mt][nt];
                        const int traj = trow0 + nt * 16 + l16;
                        const int kb = wgrp * 128 + mt * 32 + q * 8;
                        f32x4 xv = x_[mt][nt] + cw * kacc[mt][nt];
                        st4bf(XsB + swz(traj, kb), xv[0], xv[1], xv[2], xv[3]);
                    }
                }
            } else {
                const float d6 = dt * (1.f / 6.f);
                #pragma unroll
                for (int mt = 0; mt < 4; ++mt) {
                    #pragma unroll
                    for (int nt = 0; nt < 2; ++nt) {
                        const int traj = trow0 + nt * 16 + l16;
                        const int lat  = wgrp * 64 + mt * 16 + q * 4;
                        const int kb = wgrp * 128 + mt * 32 + q * 8;
                        f32x4 xv = x_[mt][nt] + d6 * (ksum[mt][nt] + kacc[mt][nt]);
                        x_[mt][nt] = xv;
                        st4bf(XsB + swz(traj, kb), xv[0], xv[1], xv[2], xv[3]);
                        *(float4*)(out + ((size_t)(grow0 + traj) * TSTEPS + (step + 1)) * LAT + lat)
                            = make_float4(xv[0], xv[1], xv[2], xv[3]);
                    }
                }
            }
            __syncthreads();   // Xs fully written before next eval reads it
        }
    }
}

extern "C" void kernel_launch(void* const* d_in, const int* in_sizes, int n_in,
                              void* d_out, int out_size, void* d_ws, size_t ws_size,
                              hipStream_t stream) {
    (void)in_sizes; (void)n_in; (void)out_size; (void)ws_size;
    const float* fp = (const float*)d_in[0];
    const float* ts = (const float*)d_in[1];
    const float* W1 = (const float*)d_in[2];
    const float* b1 = (const float*)d_in[3];
    const float* W2 = (const float*)d_in[4];
    float* out = (float*)d_out;

    __hip_bfloat16* W1p = (__hip_bfloat16*)d_ws;                 // 512 KB
    __hip_bfloat16* W2p = W1p + (size_t)HID * LAT;               // 512 KB

    // W1: n-dim = HID, k-dim = LAT; src W1 is [LAT][HID] = [K][N]
    pack_kernel<<<(HID * LAT) / 256, 256, 0, stream>>>(W1, W1p, HID, LAT);
    // W2: n-dim = LAT, k-dim = HID; src W2 is [HID][LAT] = [K][N]
    pack_kernel<<<(HID * LAT) / 256, 256, 0, stream>>>(W2, W2p, LAT, HID);

    ode_kernel<<<NBLK, 512, 0, stream>>>(fp, ts, W1p, b1, W2p, out);
}

// Round 3
// 901.031 us; speedup vs baseline: 2.6533x; 1.3416x over previous
//
#include <hip/hip_runtime.h>
#include <hip/hip_bf16.h>

// Problem constants (fp32 I/O; bf16 internally for MFMA)
#define LAT    256
#define HID    1024
#define TSTEPS 10
#define MTOT   16384            // 32*512 trajectory rows (corrcoef rows sliced away)
#define RPB    64               // rows per block
#define NBLK   (MTOT/RPB)       // 256 blocks = 1 per CU
#define CHUNK  256              // HIDDEN chunk held in LDS
#define NCHUNK (HID/CHUNK)      // 4
#define C2L2E  2.885390081777927f   // 2*log2(e): tanh(v) via exp2(C*v)

typedef short bf16x8 __attribute__((ext_vector_type(8)));
typedef float f32x4  __attribute__((ext_vector_type(4)));

// pack 4 f32 -> 4 bf16 (RNE via v_cvt_pk_bf16_f32) -> one ds_write_b64
__device__ __forceinline__ void st4bf(char* p, f32x4 v) {
    __hip_bfloat162 lo = __float22bfloat162_rn(make_float2(v[0], v[1]));
    __hip_bfloat162 hi = __float22bfloat162_rn(make_float2(v[2], v[3]));
    unsigned int ulo, uhi;
    __builtin_memcpy(&ulo, &lo, 4);
    __builtin_memcpy(&uhi, &hi, 4);
    unsigned long long u = (unsigned long long)ulo | ((unsigned long long)uhi << 32);
    *(unsigned long long*)p = u;
}

// ---- weight repack: src [K][N] f32  ->  dst fragment-linear bf16 tiles ----
// Tile (tn, tk) = 16 n-rows x 32 k-cols, lane-ordered: one wave fragment =
// one coalesced 1 KB burst, directly MFMA-A-operand shaped.
// dst[(tn*(K/32)+tk)*512 + (q*16+l16)*8 + j] = bf16(src[(tk*32+q*8+j)*N + tn*16+l16])
__global__ void pack_kernel(const float* __restrict__ src,
                            __hip_bfloat16* __restrict__ dst,
                            int N, int K) {
    int i = blockIdx.x * blockDim.x + threadIdx.x;
    if (i >= N * K) return;
    int KT   = K >> 5;
    int tile = i >> 9, wi = i & 511;
    int lane8 = wi >> 3, j = wi & 7;
    int q = lane8 >> 4, l16 = lane8 & 15;
    int tn = tile / KT, tk = tile - tn * KT;
    int n = tn * 16 + l16;
    int k = tk * 32 + q * 8 + j;
    dst[i] = __float2bfloat16(src[(size_t)k * N + n]);
}

// ---- persistent fused RK4 integrator, 16 waves (4/SIMD) ------------------
// 256 blocks x 1024 threads. Wave split: wtraj = wave&1 (32-traj group),
// wgrp = wave>>1 (32-wide hid slice in phase A / lat slice in phase B).
// [2][2] register blocking keeps VGPR <= 128 so all 16 waves are resident.
// Phase A: a1[hid][traj] = W1tile . Xs^T  -> tanh -> Hc (LDS, dbuf)
// Phase B: kacc[lat][traj] += W2tile . Hc^T
// All LDS addrs are (per-lane base) XOR (compile-time const).
__global__ __launch_bounds__(1024, 4)
void ode_kernel(const float* __restrict__ fp,
                const float* __restrict__ ts,
                const __hip_bfloat16* __restrict__ W1p,   // [HID/16][LAT/32] tiles
                const float* __restrict__ bias1,
                const __hip_bfloat16* __restrict__ W2p,   // [LAT/16][HID/32] tiles
                float* __restrict__ out) {
    __shared__ __align__(16) unsigned short Xs_s[64 * 256];      // 32 KB
    __shared__ __align__(16) unsigned short Hc_s[2][64 * 256];   // 64 KB
    __shared__ __align__(16) float bsc_s[HID];                   //  4 KB prescaled bias
    char* XsB = (char*)Xs_s;

    const int tid   = threadIdx.x;
    const int lane  = tid & 63;
    const int wave  = tid >> 6;           // 0..15
    const int wtraj = wave & 1;
    const int wgrp  = wave >> 1;          // 0..7
    const int q = lane >> 4, l16 = lane & 15;
    const int grow0 = blockIdx.x * RPB;
    const int trow0 = wtraj * 32;

    // bias prescale: bsc = b1 * 2log2e (tanh arg fold)
    if (tid < HID / 4) {
        float4 b = ((const float4*)bias1)[tid];
        ((float4*)bsc_s)[tid] = make_float4(b.x * C2L2E, b.y * C2L2E,
                                            b.z * C2L2E, b.w * C2L2E);
    }

    // per-thread swizzled base offsets (XOR-composable with const cols)
    int rbase[2], wbase[2];
    #pragma unroll
    for (int nt = 0; nt < 2; ++nt) {
        const int row = trow0 + nt * 16 + l16;
        const int msk = (row & 7) << 4;
        rbase[nt] = row * 512 + ((q * 16) ^ msk);                 // reads: ^ (kk*64)
        wbase[nt] = row * 512 + ((wgrp * 64) ^ (q * 8) ^ msk);    // writes: ^ (mt*32)
    }

    // Per-thread state: traj = trow0 + nt*16 + l16, lat = wgrp*32 + mt*16 + q*4 + r
    f32x4 x_[2][2], ksum[2][2], kacc[2][2];

    #pragma unroll
    for (int mt = 0; mt < 2; ++mt) {
        #pragma unroll
        for (int nt = 0; nt < 2; ++nt) {
            const int traj = trow0 + nt * 16 + l16;
            const int lat  = wgrp * 32 + mt * 16 + q * 4;
            float4 v = *(const float4*)(fp + (size_t)(grow0 + traj) * LAT + lat);
            x_[mt][nt] = (f32x4){v.x, v.y, v.z, v.w};
            *(float4*)(out + ((size_t)(grow0 + traj) * TSTEPS) * LAT + lat) = v;
            st4bf(XsB + (wbase[nt] ^ (mt * 32)), x_[mt][nt]);
        }
    }
    __syncthreads();

    const __hip_bfloat16* w1l = W1p + lane * 8;
    const __hip_bfloat16* w2l = W2p + lane * 8;

    #pragma unroll 1
    for (int step = 0; step < TSTEPS - 1; ++step) {
        const float dt = ts[step + 1] - ts[step];

        #pragma unroll 1
        for (int s = 0; s < 4; ++s) {
            #pragma unroll
            for (int mt = 0; mt < 2; ++mt) {
                kacc[mt][0] = (f32x4){0.f, 0.f, 0.f, 0.f};
                kacc[mt][1] = (f32x4){0.f, 0.f, 0.f, 0.f};
            }

            #pragma unroll 1
            for (int kc = 0; kc < NCHUNK; ++kc) {
                char* HcB = (kc & 1) ? (char*)Hc_s[1] : (char*)Hc_s[0];

                // ---- phase A: a1 = W1 . Xs^T for this chunk ----
                const __hip_bfloat16* w1c = w1l + (size_t)((kc * 16 + wgrp * 2) * 8) * 512;
                f32x4 a1[2][2];
                #pragma unroll
                for (int mt = 0; mt < 2; ++mt) {
                    a1[mt][0] = (f32x4){0.f, 0.f, 0.f, 0.f};
                    a1[mt][1] = (f32x4){0.f, 0.f, 0.f, 0.f};
                }
                #pragma unroll
                for (int kk = 0; kk < 8; ++kk) {
                    bf16x8 w1f0 = *(const bf16x8*)(w1c + (0 * 8 + kk) * 512);
                    bf16x8 w1f1 = *(const bf16x8*)(w1c + (1 * 8 + kk) * 512);
                    bf16x8 xf0  = *(const bf16x8*)(XsB + (rbase[0] ^ (kk * 64)));
                    bf16x8 xf1  = *(const bf16x8*)(XsB + (rbase[1] ^ (kk * 64)));
                    a1[0][0] = __builtin_amdgcn_mfma_f32_16x16x32_bf16(w1f0, xf0, a1[0][0], 0, 0, 0);
                    a1[0][1] = __builtin_amdgcn_mfma_f32_16x16x32_bf16(w1f0, xf1, a1[0][1], 0, 0, 0);
                    a1[1][0] = __builtin_amdgcn_mfma_f32_16x16x32_bf16(w1f1, xf0, a1[1][0], 0, 0, 0);
                    a1[1][1] = __builtin_amdgcn_mfma_f32_16x16x32_bf16(w1f1, xf1, a1[1][1], 0, 0, 0);
                }

                // tanh (no divide): t = exp2(C*a + bsc); th = 1 - 2*rcp(t+1)
                #pragma unroll
                for (int mt = 0; mt < 2; ++mt) {
                    f32x4 bb = *(const f32x4*)((char*)bsc_s +
                                  (kc * 1024 + wgrp * 128 + mt * 64 + q * 16));
                    #pragma unroll
                    for (int nt = 0; nt < 2; ++nt) {
                        f32x4 th;
                        #pragma unroll
                        for (int r = 0; r < 4; ++r) {
                            float pre = fmaf(a1[mt][nt][r], C2L2E, bb[r]);
                            float e   = __builtin_amdgcn_exp2f(pre);
                            float rc  = __builtin_amdgcn_rcpf(e + 1.f);
                            th[r] = fmaf(-2.f, rc, 1.f);
                        }
                        st4bf(HcB + (wbase[nt] ^ (mt * 32)), th);
                    }
                }
                __syncthreads();   // Hc[kc] ready (distance-2 fences dbuf reuse)

                // ---- phase B: kacc += W2 . Hc^T ----
                const __hip_bfloat16* w2c = w2l + (size_t)((wgrp * 2) * 32 + kc * 8) * 512;
                #pragma unroll
                for (int kk = 0; kk < 8; ++kk) {
                    bf16x8 w2f0 = *(const bf16x8*)(w2c + (0 * 32 + kk) * 512);
                    bf16x8 w2f1 = *(const bf16x8*)(w2c + (1 * 32 + kk) * 512);
                    bf16x8 hf0  = *(const bf16x8*)(HcB + (rbase[0] ^ (kk * 64)));
                    bf16x8 hf1  = *(const bf16x8*)(HcB + (rbase[1] ^ (kk * 64)));
                    kacc[0][0] = __builtin_amdgcn_mfma_f32_16x16x32_bf16(w2f0, hf0, kacc[0][0], 0, 0, 0);
                    kacc[0][1] = __builtin_amdgcn_mfma_f32_16x16x32_bf16(w2f0, hf1, kacc[0][1], 0, 0, 0);
                    kacc[1][0] = __builtin_amdgcn_mfma_f32_16x16x32_bf16(w2f1, hf0, kacc[1][0], 0, 0, 0);
                    kacc[1][1] = __builtin_amdgcn_mfma_f32_16x16x32_bf16(w2f1, hf1, kacc[1][1], 0, 0, 0);
                }
                // no trailing barrier: next chunk writes the other Hc buffer.
            }

            // ---------------- RK4 combine + next stage input ----------------
            if (s < 3) {
                const float cw = (s == 2) ? dt : 0.5f * dt;
                #pragma unroll
                for (int mt = 0; mt < 2; ++mt) {
                    #pragma unroll
                    for (int nt = 0; nt < 2; ++nt) {
                        if (s == 0) ksum[mt][nt] = kacc[mt][nt];
                        else        ksum[mt][nt] += 2.f * kacc[mt][nt];
                        f32x4 xv = x_[mt][nt] + cw * kacc[mt][nt];
                        st4bf(XsB + (wbase[nt] ^ (mt * 32)), xv);
                    }
                }
            } else {
                const float d6 = dt * (1.f / 6.f);
                #pragma unroll
                for (int mt = 0; mt < 2; ++mt) {
                    #pragma unroll
                    for (int nt = 0; nt < 2; ++nt) {
                        const int traj = trow0 + nt * 16 + l16;
                        const int lat  = wgrp * 32 + mt * 16 + q * 4;
                        f32x4 xv = x_[mt][nt] + d6 * (ksum[mt][nt] + kacc[mt][nt]);
                        x_[mt][nt] = xv;
                        st4bf(XsB + (wbase[nt] ^ (mt * 32)), xv);
                        *(float4*)(out + ((size_t)(grow0 + traj) * TSTEPS + (step + 1)) * LAT + lat)
                            = make_float4(xv[0], xv[1], xv[2], xv[3]);
                    }
                }
            }
            __syncthreads();   // Xs fully written before next eval reads it
        }
    }
}

extern "C" void kernel_launch(void* const* d_in, const int* in_sizes, int n_in,
                              void* d_out, int out_size, void* d_ws, size_t ws_size,
                              hipStream_t stream) {
    (void)in_sizes; (void)n_in; (void)out_size; (void)ws_size;
    const float* fp = (const float*)d_in[0];
    const float* ts = (const float*)d_in[1];
    const float* W1 = (const float*)d_in[2];
    const float* b1 = (const float*)d_in[3];
    const float* W2 = (const float*)d_in[4];
    float* out = (float*)d_out;

    __hip_bfloat16* W1p = (__hip_bfloat16*)d_ws;                 // 512 KB
    __hip_bfloat16* W2p = W1p + (size_t)HID * LAT;               // 512 KB

    // W1: n-dim = HID, k-dim = LAT; src W1 is [LAT][HID] = [K][N]
    pack_kernel<<<(HID * LAT) / 256, 256, 0, stream>>>(W1, W1p, HID, LAT);
    // W2: n-dim = LAT, k-dim = HID; src W2 is [HID][LAT] = [K][N]
    pack_kernel<<<(HID * LAT) / 256, 256, 0, stream>>>(W2, W2p, LAT, HID);

    ode_kernel<<<NBLK, 1024, 0, stream>>>(fp, ts, W1p, b1, W2p, out);
}